// Round 2
// baseline (390.083 us; speedup 1.0000x reference)
//
#include <hip/hip_runtime.h>
#include <hip/hip_bf16.h>

typedef unsigned short u16;
typedef unsigned int u32;
typedef __attribute__((ext_vector_type(8))) short bf16x8;
typedef __attribute__((ext_vector_type(8))) unsigned short u16x8;
typedef __attribute__((ext_vector_type(4))) unsigned short u16x4;
typedef __attribute__((ext_vector_type(4))) float f32x4;

#define DEVI __device__ __forceinline__

static constexpr int Bn = 8, Tn = 1024, Fn = 1024, Hn = 16, DKn = 64;
static constexpr int Mtot = Bn * Tn;  // 8192

DEVI u16 f2bf(float x) {
  unsigned u = __builtin_bit_cast(unsigned, x);
  u += 0x7fffu + ((u >> 16) & 1u);
  return (u16)(u >> 16);
}

DEVI u32 cvt_pk_bf16(float lo, float hi) {
  u32 r;
  asm("v_cvt_pk_bf16_f32 %0, %1, %2" : "=v"(r) : "v"(lo), "v"(hi));
  return r;
}

DEVI f32x4 mfma16(bf16x8 a, bf16x8 b, f32x4 c) {
  return __builtin_amdgcn_mfma_f32_16x16x32_bf16(a, b, c, 0, 0, 0);
}

typedef const __attribute__((address_space(1))) void GAS;
typedef __attribute__((address_space(3))) void LAS;
#define GLL16(gp, lp) __builtin_amdgcn_global_load_lds((GAS*)(gp), (LAS*)(lp), 16, 0, 0)

// ---------------- fp32 -> bf16 conversion ----------------
__global__ __launch_bounds__(256) void cvt_f32_bf16(const float* __restrict__ in,
                                                    u16* __restrict__ out, int n) {
  int i = (blockIdx.x * 256 + threadIdx.x) * 8;
  if (i >= n) return;
  const float4* p = reinterpret_cast<const float4*>(in + i);
  float4 a = p[0], b = p[1];
  float v[8] = {a.x, a.y, a.z, a.w, b.x, b.y, b.z, b.w};
  u16x8 r;
#pragma unroll
  for (int j = 0; j < 8; j++) r[j] = f2bf(v[j]);
  *reinterpret_cast<u16x8*>(out + i) = r;
}

// ---------------- GEMM  C[M,N] = (A[M,K] * W[N,K]^T + bias) * oscale ----------------
// MODE 0: write bf16 (B,H,T,DK)  (Q/K proj; Q uses oscale = 1/sqrt(dk)*log2e)
// MODE 1: write bf16 (B,H,DK,T)  (V proj, transposed)
// MODE 2: write fp32 (M,N) = (acc+bias)*mask[m]  (out proj)
template <int MODE>
__global__ __launch_bounds__(256) void gemm_bt(const u16* __restrict__ A,
                                               const u16* __restrict__ Bw,
                                               const float* __restrict__ bias,
                                               const float* __restrict__ mask,
                                               u16* __restrict__ Obf,
                                               float* __restrict__ Of,
                                               float oscale) {
  constexpr int Kd = 1024;
  __shared__ u16 sA[2][128 * 32];
  __shared__ u16 sB[2][128 * 32];
  const int tid = threadIdx.x;
  const int l = tid & 63, w = tid >> 6;
  const int m0 = blockIdx.x * 128;  // 64 tiles
  const int n0 = blockIdx.y * 128;  // 8 tiles
  const int srow = l >> 2, sslot = l & 3;
  const int wr = w >> 1, wc = w & 1;
  const int lr = l & 15, g = l >> 4;

  f32x4 acc[4][4];
#pragma unroll
  for (int i = 0; i < 4; i++)
#pragma unroll
    for (int j = 0; j < 4; j++) acc[i][j] = f32x4{0.f, 0.f, 0.f, 0.f};

  auto stage = [&](int bf, int kt) {
    const u16* Ab = A + (size_t)m0 * Kd + kt * 32;
    const u16* Bb = Bw + (size_t)n0 * Kd + kt * 32;
#pragma unroll
    for (int i = 0; i < 2; i++) {
      int row = i * 64 + w * 16 + srow;
      GLL16(Ab + (size_t)row * Kd + sslot * 8, &sA[bf][i * 2048 + w * 512]);
      GLL16(Bb + (size_t)row * Kd + sslot * 8, &sB[bf][i * 2048 + w * 512]);
    }
  };

  stage(0, 0);
  __syncthreads();
  int cur = 0;
  for (int kt = 0; kt < 32; ++kt) {
    if (kt + 1 < 32) stage(cur ^ 1, kt + 1);
    bf16x8 af[4], bfr[4];
#pragma unroll
    for (int mi = 0; mi < 4; mi++)
      af[mi] = *reinterpret_cast<const bf16x8*>(&sA[cur][(wr * 64 + mi * 16 + lr) * 32 + g * 8]);
#pragma unroll
    for (int ni = 0; ni < 4; ni++)
      bfr[ni] = *reinterpret_cast<const bf16x8*>(&sB[cur][(wc * 64 + ni * 16 + lr) * 32 + g * 8]);
#pragma unroll
    for (int mi = 0; mi < 4; mi++)
#pragma unroll
      for (int ni = 0; ni < 4; ni++) acc[mi][ni] = mfma16(af[mi], bfr[ni], acc[mi][ni]);
    __syncthreads();
    cur ^= 1;
  }

  // epilogue
  int ncol[4];
  float bv[4];
#pragma unroll
  for (int ni = 0; ni < 4; ni++) {
    ncol[ni] = n0 + wc * 64 + ni * 16 + lr;
    bv[ni] = bias[ncol[ni]];
  }
#pragma unroll
  for (int mi = 0; mi < 4; mi++) {
    const int mb = m0 + wr * 64 + mi * 16 + g * 4;
    if constexpr (MODE == 1) {
      // V^T: t consecutive in j -> pack 4 bf16 per store
#pragma unroll
      for (int ni = 0; ni < 4; ni++) {
        const int n = ncol[ni];
        const int h = n >> 6, dk = n & 63;
        u16x4 pk;
#pragma unroll
        for (int j = 0; j < 4; j++) pk[j] = f2bf(acc[mi][ni][j] + bv[ni]);
        const int b = mb >> 10, t = mb & 1023;
        size_t idx = (((size_t)b * 16 + h) * 64 + dk) * 1024 + t;
        *reinterpret_cast<u16x4*>(Obf + idx) = pk;
      }
    } else {
#pragma unroll
      for (int j = 0; j < 4; j++) {
        const int m = mb + j;
        const int b = m >> 10, t = m & 1023;
        float mk = 0.f;
        if constexpr (MODE == 2) mk = mask[m];
#pragma unroll
        for (int ni = 0; ni < 4; ni++) {
          const int n = ncol[ni];
          float v = acc[mi][ni][j] + bv[ni];
          if constexpr (MODE == 0) {
            const int h = n >> 6, dk = n & 63;
            Obf[((((size_t)b * 16 + h) * 1024 + t) * 64) + dk] = f2bf(v * oscale);
          } else {
            Of[(size_t)m * 1024 + n] = v * mk;
          }
        }
      }
    }
  }
}

// ---------------- flash attention (swapped-operand softmax) ----------------
// grid: 2048 blocks (bh = blk>>4, qtile = blk&15); 256 thr = 4 indep waves x 16 q-rows.
// Each lane owns ONE q-row (q = lane&15); S^T = mfma(K,Q) puts the full kv-slice
// of that row in-lane -> softmax reduce = in-lane max + 2 shfl; sum deferred.
// P written to per-wave LDS as rows [q][kv] (4 x ds_write_b64, XOR-swizzled),
// re-read as PV B-frags (2 x ds_read_b128, conflict-free). PV computes
// O^T = mfma(V^T, P) so the alpha/lsum rescale stays lane-local.
__global__ __launch_bounds__(256) void flash_attn(const u16* __restrict__ Qb,
                                                  const u16* __restrict__ Kb,
                                                  const u16* __restrict__ Vt,
                                                  u16* __restrict__ ctx) {
  __shared__ u16 pbuf[4][16 * 64];
  const int tid = threadIdx.x, l = tid & 63, w = tid >> 6;
  const int lr = l & 15, g = l >> 4;
  const int qt = blockIdx.x & 15, bh = blockIdx.x >> 4;
  const u16* Qh = Qb + (size_t)bh * (Tn * DKn);
  const u16* Kh = Kb + (size_t)bh * (Tn * DKn);
  const u16* Vh = Vt + (size_t)bh * (Tn * DKn);

  const int qrow = qt * 64 + w * 16 + lr;
  bf16x8 aq0 = *reinterpret_cast<const bf16x8*>(Qh + (size_t)qrow * 64 + g * 8);
  bf16x8 aq1 = *reinterpret_cast<const bf16x8*>(Qh + (size_t)qrow * 64 + 32 + g * 8);

  float mrow = -1e30f, lsum = 0.f;
  f32x4 of[4];
#pragma unroll
  for (int c = 0; c < 4; c++) of[c] = f32x4{0.f, 0.f, 0.f, 0.f};

  char* pb = (char*)&pbuf[w][0];
  const int swz = (lr & 7) << 4;
  int wadr[4];
#pragma unroll
  for (int c = 0; c < 4; c++) wadr[c] = lr * 128 + (((c * 16 + g * 4) * 2) ^ swz);
  const int radr0 = lr * 128 + ((g * 16) ^ swz);
  const int radr1 = lr * 128 + ((64 + g * 16) ^ swz);

  for (int kv0 = 0; kv0 < Tn; kv0 += 64) {
    // S^T = K . Q^T  (Q pre-scaled by 1/sqrt(dk)*log2e in the projection)
    f32x4 sf[4];
    __builtin_amdgcn_s_setprio(1);
#pragma unroll
    for (int c = 0; c < 4; c++) {
      const u16* kr = Kh + (size_t)(kv0 + c * 16 + lr) * 64;
      bf16x8 k0 = *reinterpret_cast<const bf16x8*>(kr + g * 8);
      bf16x8 k1 = *reinterpret_cast<const bf16x8*>(kr + 32 + g * 8);
      f32x4 z = f32x4{0.f, 0.f, 0.f, 0.f};
      z = mfma16(k0, aq0, z);
      z = mfma16(k1, aq1, z);
      sf[c] = z;
    }
    __builtin_amdgcn_s_setprio(0);

    // online softmax: one scalar row-state per lane
    f32x4 mx4 = sf[0];
#pragma unroll
    for (int c = 1; c < 4; c++)
#pragma unroll
      for (int j = 0; j < 4; j++) mx4[j] = fmaxf(mx4[j], sf[c][j]);
    float mx = fmaxf(fmaxf(mx4[0], mx4[1]), fmaxf(mx4[2], mx4[3]));
    mx = fmaxf(mx, __shfl_xor(mx, 16));
    mx = fmaxf(mx, __shfl_xor(mx, 32));
    const float mn = fmaxf(mrow, mx);
    const float alpha = exp2f(mrow - mn);
    mrow = mn;

    float rs = 0.f;
#pragma unroll
    for (int c = 0; c < 4; c++)
#pragma unroll
      for (int j = 0; j < 4; j++) {
        float p = exp2f(sf[c][j] - mn);
        sf[c][j] = p;
        rs += p;
      }
    lsum = lsum * alpha + rs;
#pragma unroll
    for (int c = 0; c < 4; c++)
#pragma unroll
      for (int j = 0; j < 4; j++) of[c][j] *= alpha;

    // P -> LDS rows [q=lr][kv], bf16, b64 writes
#pragma unroll
    for (int c = 0; c < 4; c++) {
      uint2 pk;
      pk.x = cvt_pk_bf16(sf[c][0], sf[c][1]);
      pk.y = cvt_pk_bf16(sf[c][2], sf[c][3]);
      *reinterpret_cast<uint2*>(pb + wadr[c]) = pk;
    }
    bf16x8 ap0 = *reinterpret_cast<const bf16x8*>(pb + radr0);
    bf16x8 ap1 = *reinterpret_cast<const bf16x8*>(pb + radr1);

    // O^T += V^T . P^T
    __builtin_amdgcn_s_setprio(1);
#pragma unroll
    for (int d0 = 0; d0 < 4; d0++) {
      const u16* vr = Vh + (size_t)(d0 * 16 + lr) * 1024 + kv0;
      bf16x8 v0 = *reinterpret_cast<const bf16x8*>(vr + g * 8);
      bf16x8 v1 = *reinterpret_cast<const bf16x8*>(vr + 32 + g * 8);
      of[d0] = mfma16(v0, ap0, of[d0]);
      of[d0] = mfma16(v1, ap1, of[d0]);
    }
    __builtin_amdgcn_s_setprio(0);
  }

  // epilogue: lsum group-reduce, normalize, store ctx (B*T, F) bf16
  lsum += __shfl_xor(lsum, 16);
  lsum += __shfl_xor(lsum, 32);
  const float inv = 1.0f / lsum;
  const int b = bh >> 4, h = bh & 15;
  const size_t base = ((size_t)b * 1024 + qrow) * 1024 + h * 64;
#pragma unroll
  for (int d0 = 0; d0 < 4; d0++) {
    uint2 pk;
    pk.x = cvt_pk_bf16(of[d0][0] * inv, of[d0][1] * inv);
    pk.y = cvt_pk_bf16(of[d0][2] * inv, of[d0][3] * inv);
    *reinterpret_cast<uint2*>(ctx + base + d0 * 16 + g * 4) = pk;
  }
}

// ---------------- launch ----------------
extern "C" void kernel_launch(void* const* d_in, const int* in_sizes, int n_in,
                              void* d_out, int out_size, void* d_ws, size_t ws_size,
                              hipStream_t stream) {
  const float* query = (const float*)d_in[0];
  const float* key = (const float*)d_in[1];
  const float* value = (const float*)d_in[2];
  const float* mask = (const float*)d_in[3];
  const float* Wq = (const float*)d_in[4];
  const float* bq = (const float*)d_in[5];
  const float* Wk = (const float*)d_in[6];
  const float* bk = (const float*)d_in[7];
  const float* Wv = (const float*)d_in[8];
  const float* bv = (const float*)d_in[9];
  const float* Wo = (const float*)d_in[10];
  const float* bo = (const float*)d_in[11];
  (void)in_sizes; (void)n_in; (void)out_size; (void)ws_size;

  u16* ws = (u16*)d_ws;
  const size_t MB8 = (size_t)8 << 20;  // 8M u16 = 16 MB
  u16* Xq = ws;                        // reused as ctx after Q-proj
  u16* Xk = ws + MB8;
  u16* Xv = ws + 2 * MB8;
  u16* Wqb = ws + 3 * MB8;
  u16* Wkb = Wqb + (1 << 20);
  u16* Wvb = Wkb + (1 << 20);
  u16* Wob = Wvb + (1 << 20);
  u16* Qb = Wob + (1 << 20);
  u16* Kb = Qb + MB8;
  u16* Vtb = Kb + MB8;
  u16* ctx = Xq;

  const int NX = Mtot * Fn;  // 8388608
  const int NW = Fn * Fn;    // 1048576
  cvt_f32_bf16<<<NX / (8 * 256), 256, 0, stream>>>(query, Xq, NX);
  cvt_f32_bf16<<<NX / (8 * 256), 256, 0, stream>>>(key, Xk, NX);
  cvt_f32_bf16<<<NX / (8 * 256), 256, 0, stream>>>(value, Xv, NX);
  cvt_f32_bf16<<<NW / (8 * 256), 256, 0, stream>>>(Wq, Wqb, NW);
  cvt_f32_bf16<<<NW / (8 * 256), 256, 0, stream>>>(Wk, Wkb, NW);
  cvt_f32_bf16<<<NW / (8 * 256), 256, 0, stream>>>(Wv, Wvb, NW);
  cvt_f32_bf16<<<NW / (8 * 256), 256, 0, stream>>>(Wo, Wob, NW);

  const float SC = 0.125f * 1.44269504089f;  // 1/sqrt(DK) * log2(e)
  dim3 gg(Mtot / 128, Fn / 128);
  gemm_bt<0><<<gg, 256, 0, stream>>>(Xq, Wqb, bq, nullptr, Qb, nullptr, SC);
  gemm_bt<0><<<gg, 256, 0, stream>>>(Xk, Wkb, bk, nullptr, Kb, nullptr, 1.0f);
  gemm_bt<1><<<gg, 256, 0, stream>>>(Xv, Wvb, bv, nullptr, Vtb, nullptr, 1.0f);

  flash_attn<<<Bn * Hn * (Tn / 64), 256, 0, stream>>>(Qb, Kb, Vtb, ctx);

  gemm_bt<2><<<gg, 256, 0, stream>>>(ctx, Wob, bo, mask, nullptr, (float*)d_out, 1.0f);
}

// Round 3
// 238.335 us; speedup vs baseline: 1.6367x; 1.6367x over previous
//
#include <hip/hip_runtime.h>
#include <hip/hip_bf16.h>

typedef unsigned short u16;
typedef unsigned int u32;
typedef __attribute__((ext_vector_type(8))) short bf16x8;
typedef __attribute__((ext_vector_type(8))) unsigned short u16x8;
typedef __attribute__((ext_vector_type(4))) unsigned short u16x4;
typedef __attribute__((ext_vector_type(4))) float f32x4;

#define DEVI __device__ __forceinline__

static constexpr int Bn = 8, Tn = 1024, Fn = 1024, Hn = 16, DKn = 64;
static constexpr int Mtot = Bn * Tn;  // 8192

DEVI u16 f2bf(float x) {
  unsigned u = __builtin_bit_cast(unsigned, x);
  u += 0x7fffu + ((u >> 16) & 1u);
  return (u16)(u >> 16);
}

DEVI u32 cvt_pk_bf16(float lo, float hi) {
  u32 r;
  asm("v_cvt_pk_bf16_f32 %0, %1, %2" : "=v"(r) : "v"(lo), "v"(hi));
  return r;
}

DEVI f32x4 mfma16(bf16x8 a, bf16x8 b, f32x4 c) {
  return __builtin_amdgcn_mfma_f32_16x16x32_bf16(a, b, c, 0, 0, 0);
}

typedef const __attribute__((address_space(1))) void GAS;
typedef __attribute__((address_space(3))) void LAS;
#define GLL16(gp, lp) __builtin_amdgcn_global_load_lds((GAS*)(gp), (LAS*)(lp), 16, 0, 0)

// ---------------- fp32 -> bf16 conversion ----------------
__global__ __launch_bounds__(256) void cvt_f32_bf16(const float* __restrict__ in,
                                                    u16* __restrict__ out, int n) {
  int i = (blockIdx.x * 256 + threadIdx.x) * 8;
  if (i >= n) return;
  const float4* p = reinterpret_cast<const float4*>(in + i);
  float4 a = p[0], b = p[1];
  float v[8] = {a.x, a.y, a.z, a.w, b.x, b.y, b.z, b.w};
  u16x8 r;
#pragma unroll
  for (int j = 0; j < 8; j++) r[j] = f2bf(v[j]);
  *reinterpret_cast<u16x8*>(out + i) = r;
}

// ---------------- GEMM  C[M,N] = (A[M,K] * W[N,K]^T + bias) * oscale ----------------
// MODE 0: write bf16 (B,H,T,DK)  (Q/K proj; Q uses oscale = 1/sqrt(dk)*log2e)
// MODE 1: write bf16 (B,H,DK,T)  (V proj, transposed)
// MODE 2: write fp32 (M,N) = (acc+bias)*mask[m]  (out proj)
template <int MODE>
__global__ __launch_bounds__(256) void gemm_bt(const u16* __restrict__ A,
                                               const u16* __restrict__ Bw,
                                               const float* __restrict__ bias,
                                               const float* __restrict__ mask,
                                               u16* __restrict__ Obf,
                                               float* __restrict__ Of,
                                               float oscale) {
  constexpr int Kd = 1024;
  __shared__ u16 sA[2][128 * 32];
  __shared__ u16 sB[2][128 * 32];
  const int tid = threadIdx.x;
  const int l = tid & 63, w = tid >> 6;
  const int m0 = blockIdx.x * 128;  // 64 tiles
  const int n0 = blockIdx.y * 128;  // 8 tiles
  const int srow = l >> 2, sslot = l & 3;
  const int wr = w >> 1, wc = w & 1;
  const int lr = l & 15, g = l >> 4;

  f32x4 acc[4][4];
#pragma unroll
  for (int i = 0; i < 4; i++)
#pragma unroll
    for (int j = 0; j < 4; j++) acc[i][j] = f32x4{0.f, 0.f, 0.f, 0.f};

  auto stage = [&](int bf, int kt) {
    const u16* Ab = A + (size_t)m0 * Kd + kt * 32;
    const u16* Bb = Bw + (size_t)n0 * Kd + kt * 32;
#pragma unroll
    for (int i = 0; i < 2; i++) {
      int row = i * 64 + w * 16 + srow;
      GLL16(Ab + (size_t)row * Kd + sslot * 8, &sA[bf][i * 2048 + w * 512]);
      GLL16(Bb + (size_t)row * Kd + sslot * 8, &sB[bf][i * 2048 + w * 512]);
    }
  };

  stage(0, 0);
  __syncthreads();
  int cur = 0;
  for (int kt = 0; kt < 32; ++kt) {
    if (kt + 1 < 32) stage(cur ^ 1, kt + 1);
    bf16x8 af[4], bfr[4];
#pragma unroll
    for (int mi = 0; mi < 4; mi++)
      af[mi] = *reinterpret_cast<const bf16x8*>(&sA[cur][(wr * 64 + mi * 16 + lr) * 32 + g * 8]);
#pragma unroll
    for (int ni = 0; ni < 4; ni++)
      bfr[ni] = *reinterpret_cast<const bf16x8*>(&sB[cur][(wc * 64 + ni * 16 + lr) * 32 + g * 8]);
#pragma unroll
    for (int mi = 0; mi < 4; mi++)
#pragma unroll
      for (int ni = 0; ni < 4; ni++) acc[mi][ni] = mfma16(af[mi], bfr[ni], acc[mi][ni]);
    __syncthreads();
    cur ^= 1;
  }

  // epilogue
  int ncol[4];
  float bv[4];
#pragma unroll
  for (int ni = 0; ni < 4; ni++) {
    ncol[ni] = n0 + wc * 64 + ni * 16 + lr;
    bv[ni] = bias[ncol[ni]];
  }
#pragma unroll
  for (int mi = 0; mi < 4; mi++) {
    const int mb = m0 + wr * 64 + mi * 16 + g * 4;
    if constexpr (MODE == 1) {
#pragma unroll
      for (int ni = 0; ni < 4; ni++) {
        const int n = ncol[ni];
        const int h = n >> 6, dk = n & 63;
        u16x4 pk;
#pragma unroll
        for (int j = 0; j < 4; j++) pk[j] = f2bf(acc[mi][ni][j] + bv[ni]);
        const int b = mb >> 10, t = mb & 1023;
        size_t idx = (((size_t)b * 16 + h) * 64 + dk) * 1024 + t;
        *reinterpret_cast<u16x4*>(Obf + idx) = pk;
      }
    } else {
#pragma unroll
      for (int j = 0; j < 4; j++) {
        const int m = mb + j;
        const int b = m >> 10, t = m & 1023;
        float mk = 0.f;
        if constexpr (MODE == 2) mk = mask[m];
#pragma unroll
        for (int ni = 0; ni < 4; ni++) {
          const int n = ncol[ni];
          float v = acc[mi][ni][j] + bv[ni];
          if constexpr (MODE == 0) {
            const int h = n >> 6, dk = n & 63;
            Obf[((((size_t)b * 16 + h) * 1024 + t) * 64) + dk] = f2bf(v * oscale);
          } else {
            Of[(size_t)m * 1024 + n] = v * mk;
          }
        }
      }
    }
  }
}

// ---------------- flash attention (LDS-staged K/V, 2-phase pipeline) ----------------
// grid 1024 blocks; XCD-swizzled so each head's 8 q-tile blocks live on ONE XCD
// (16 heads x 256KB K/V = 4MB = per-XCD L2). Block = 4 waves x 32 q-rows = 128 rows.
// K tile [64kv][64d] and V^T tile [64d][64kv] staged via global_load_lds (linear
// dest, inverse-XOR-swizzled global source) and read as swizzled ds_read_b128
// (2-way = free). Swapped-operand softmax as before, 2 q-groups per wave.
__global__ __launch_bounds__(256, 4) void flash_attn(const u16* __restrict__ Qb,
                                                     const u16* __restrict__ Kb,
                                                     const u16* __restrict__ Vt,
                                                     u16* __restrict__ ctx) {
  __shared__ u16 sK[2][64 * 64];
  __shared__ u16 sV[2][64 * 64];
  __shared__ u16 pbuf[4][16 * 64];
  const int tid = threadIdx.x, l = tid & 63, w = tid >> 6;
  const int lr = l & 15, g = l >> 4;
  const int wg = ((blockIdx.x & 7) << 7) + (blockIdx.x >> 3);  // bijective XCD swizzle
  const int qt = wg & 7, bh = wg >> 3;
  const u16* Qh = Qb + (size_t)bh * (Tn * DKn);
  const u16* Kh = Kb + (size_t)bh * (Tn * DKn);
  const u16* Vh = Vt + (size_t)bh * (Tn * DKn);

  bf16x8 aq[2][2];
  int qrow[2];
#pragma unroll
  for (int qg = 0; qg < 2; qg++) {
    qrow[qg] = qt * 128 + w * 32 + qg * 16 + lr;
    aq[qg][0] = *reinterpret_cast<const bf16x8*>(Qh + (size_t)qrow[qg] * 64 + g * 8);
    aq[qg][1] = *reinterpret_cast<const bf16x8*>(Qh + (size_t)qrow[qg] * 64 + 32 + g * 8);
  }

  float mrow[2] = {-1e30f, -1e30f}, lsum[2] = {0.f, 0.f};
  f32x4 of[2][4];
#pragma unroll
  for (int qg = 0; qg < 2; qg++)
#pragma unroll
    for (int c = 0; c < 4; c++) of[qg][c] = f32x4{0.f, 0.f, 0.f, 0.f};

  char* pb = (char*)&pbuf[w][0];
  const int sw = (lr & 7) << 4;
  int wadr[4];
#pragma unroll
  for (int c = 0; c < 4; c++) wadr[c] = lr * 128 + (((c * 16 + g * 4) * 2) ^ sw);
  const int radr0 = lr * 128 + ((g * 16) ^ sw);
  const int radr1 = lr * 128 + ((64 + g * 16) ^ sw);

  // stage K[64][64] and V^T[64][64] tiles: linear LDS dest, source chunk
  // pre-XOR'd by (row&7) so swizzled reads land on the right data.
  auto stage = [&](int buf, int kv0) {
#pragma unroll
    for (int i = 0; i < 2; i++) {
      const int tt = i * 256 + tid;
      const int r = tt >> 3;
      const int c = (tt & 7) ^ (r & 7);
      GLL16((const char*)Kh + ((size_t)(kv0 + r) << 7) + (c << 4),
            (char*)&sK[buf][0] + i * 4096 + w * 1024);
      GLL16((const char*)Vh + ((size_t)r << 11) + kv0 * 2 + (c << 4),
            (char*)&sV[buf][0] + i * 4096 + w * 1024);
    }
  };

  stage(0, 0);
  __syncthreads();
  int cur = 0;

  for (int t = 0; t < 16; t++) {
    if (t < 15) stage(cur ^ 1, (t + 1) * 64);
    const char* kb = (const char*)&sK[cur][0];
    const char* vb = (const char*)&sV[cur][0];

    // S^T = K . Q^T for both q-groups (Q pre-scaled by 1/sqrt(dk)*log2e)
    f32x4 sf[2][4];
    __builtin_amdgcn_s_setprio(1);
#pragma unroll
    for (int c = 0; c < 4; c++) {
      const char* kr = kb + (c * 16 + lr) * 128;
      bf16x8 k0 = *reinterpret_cast<const bf16x8*>(kr + ((g * 16) ^ sw));
      bf16x8 k1 = *reinterpret_cast<const bf16x8*>(kr + ((64 + g * 16) ^ sw));
      f32x4 z0 = mfma16(k0, aq[0][0], f32x4{0.f, 0.f, 0.f, 0.f});
      sf[0][c] = mfma16(k1, aq[0][1], z0);
      f32x4 z1 = mfma16(k0, aq[1][0], f32x4{0.f, 0.f, 0.f, 0.f});
      sf[1][c] = mfma16(k1, aq[1][1], z1);
    }
    __builtin_amdgcn_s_setprio(0);

#pragma unroll
    for (int qg = 0; qg < 2; qg++) {
      // online softmax: one scalar row-state per lane
      f32x4 mx4 = sf[qg][0];
#pragma unroll
      for (int c = 1; c < 4; c++)
#pragma unroll
        for (int j = 0; j < 4; j++) mx4[j] = fmaxf(mx4[j], sf[qg][c][j]);
      float mx = fmaxf(fmaxf(mx4[0], mx4[1]), fmaxf(mx4[2], mx4[3]));
      mx = fmaxf(mx, __shfl_xor(mx, 16));
      mx = fmaxf(mx, __shfl_xor(mx, 32));
      const float mn = fmaxf(mrow[qg], mx);
      const float alpha = exp2f(mrow[qg] - mn);
      mrow[qg] = mn;

      float rs = 0.f;
#pragma unroll
      for (int c = 0; c < 4; c++)
#pragma unroll
        for (int j = 0; j < 4; j++) {
          float p = exp2f(sf[qg][c][j] - mn);
          sf[qg][c][j] = p;
          rs += p;
        }
      lsum[qg] = lsum[qg] * alpha + rs;
#pragma unroll
      for (int c = 0; c < 4; c++)
#pragma unroll
        for (int j = 0; j < 4; j++) of[qg][c][j] *= alpha;

      // P -> per-wave LDS rows [q=lr][kv] (b64, swizzled), re-read as B-frags
#pragma unroll
      for (int c = 0; c < 4; c++) {
        uint2 pk;
        pk.x = cvt_pk_bf16(sf[qg][c][0], sf[qg][c][1]);
        pk.y = cvt_pk_bf16(sf[qg][c][2], sf[qg][c][3]);
        *reinterpret_cast<uint2*>(pb + wadr[c]) = pk;
      }
      bf16x8 ap0 = *reinterpret_cast<const bf16x8*>(pb + radr0);
      bf16x8 ap1 = *reinterpret_cast<const bf16x8*>(pb + radr1);

      // O^T += V^T . P^T
      __builtin_amdgcn_s_setprio(1);
#pragma unroll
      for (int d0 = 0; d0 < 4; d0++) {
        const char* vr = vb + (d0 * 16 + lr) * 128;
        bf16x8 v0 = *reinterpret_cast<const bf16x8*>(vr + ((g * 16) ^ sw));
        bf16x8 v1 = *reinterpret_cast<const bf16x8*>(vr + ((64 + g * 16) ^ sw));
        f32x4 z = mfma16(v0, ap0, of[qg][d0]);
        of[qg][d0] = mfma16(v1, ap1, z);
      }
      __builtin_amdgcn_s_setprio(0);
    }
    __syncthreads();
    cur ^= 1;
  }

  // epilogue: lsum group-reduce, normalize, store ctx (B*T, F) bf16
  const int b = bh >> 4, h = bh & 15;
#pragma unroll
  for (int qg = 0; qg < 2; qg++) {
    float ls = lsum[qg];
    ls += __shfl_xor(ls, 16);
    ls += __shfl_xor(ls, 32);
    const float inv = 1.0f / ls;
    const size_t base = ((size_t)b * 1024 + qrow[qg]) * 1024 + h * 64;
#pragma unroll
    for (int d0 = 0; d0 < 4; d0++) {
      uint2 pk;
      pk.x = cvt_pk_bf16(of[qg][d0][0] * inv, of[qg][d0][1] * inv);
      pk.y = cvt_pk_bf16(of[qg][d0][2] * inv, of[qg][d0][3] * inv);
      *reinterpret_cast<uint2*>(ctx + base + d0 * 16 + g * 4) = pk;
    }
  }
}

// ---------------- launch ----------------
extern "C" void kernel_launch(void* const* d_in, const int* in_sizes, int n_in,
                              void* d_out, int out_size, void* d_ws, size_t ws_size,
                              hipStream_t stream) {
  const float* query = (const float*)d_in[0];
  const float* key = (const float*)d_in[1];
  const float* value = (const float*)d_in[2];
  const float* mask = (const float*)d_in[3];
  const float* Wq = (const float*)d_in[4];
  const float* bq = (const float*)d_in[5];
  const float* Wk = (const float*)d_in[6];
  const float* bk = (const float*)d_in[7];
  const float* Wv = (const float*)d_in[8];
  const float* bv = (const float*)d_in[9];
  const float* Wo = (const float*)d_in[10];
  const float* bo = (const float*)d_in[11];
  (void)in_sizes; (void)n_in; (void)out_size; (void)ws_size;

  u16* ws = (u16*)d_ws;
  const size_t MB8 = (size_t)8 << 20;  // 8M u16 = 16 MB
  u16* Xq = ws;                        // reused as ctx after Q-proj
  u16* Xk = ws + MB8;
  u16* Xv = ws + 2 * MB8;
  u16* Wqb = ws + 3 * MB8;
  u16* Wkb = Wqb + (1 << 20);
  u16* Wvb = Wkb + (1 << 20);
  u16* Wob = Wvb + (1 << 20);
  u16* Qb = Wob + (1 << 20);
  u16* Kb = Qb + MB8;
  u16* Vtb = Kb + MB8;
  u16* ctx = Xq;

  const int NX = Mtot * Fn;  // 8388608
  const int NW = Fn * Fn;    // 1048576
  cvt_f32_bf16<<<NX / (8 * 256), 256, 0, stream>>>(query, Xq, NX);
  cvt_f32_bf16<<<NX / (8 * 256), 256, 0, stream>>>(key, Xk, NX);
  cvt_f32_bf16<<<NX / (8 * 256), 256, 0, stream>>>(value, Xv, NX);
  cvt_f32_bf16<<<NW / (8 * 256), 256, 0, stream>>>(Wq, Wqb, NW);
  cvt_f32_bf16<<<NW / (8 * 256), 256, 0, stream>>>(Wk, Wkb, NW);
  cvt_f32_bf16<<<NW / (8 * 256), 256, 0, stream>>>(Wv, Wvb, NW);
  cvt_f32_bf16<<<NW / (8 * 256), 256, 0, stream>>>(Wo, Wob, NW);

  const float SC = 0.125f * 1.44269504089f;  // 1/sqrt(DK) * log2(e)
  dim3 gg(Mtot / 128, Fn / 128);
  gemm_bt<0><<<gg, 256, 0, stream>>>(Xq, Wqb, bq, nullptr, Qb, nullptr, SC);
  gemm_bt<0><<<gg, 256, 0, stream>>>(Xk, Wkb, bk, nullptr, Kb, nullptr, 1.0f);
  gemm_bt<1><<<gg, 256, 0, stream>>>(Xv, Wvb, bv, nullptr, Vtb, nullptr, 1.0f);

  flash_attn<<<Bn * Hn * (Tn / 128), 256, 0, stream>>>(Qb, Kb, Vtb, ctx);

  gemm_bt<2><<<gg, 256, 0, stream>>>(ctx, Wob, bo, mask, nullptr, (float*)d_out, 1.0f);
}

// Round 4
// 215.481 us; speedup vs baseline: 1.8103x; 1.1061x over previous
//
#include <hip/hip_runtime.h>
#include <hip/hip_bf16.h>

typedef unsigned short u16;
typedef unsigned int u32;
typedef __attribute__((ext_vector_type(8))) short bf16x8;
typedef __attribute__((ext_vector_type(8))) unsigned short u16x8;
typedef __attribute__((ext_vector_type(4))) unsigned short u16x4;
typedef __attribute__((ext_vector_type(4))) float f32x4;

#define DEVI __device__ __forceinline__

static constexpr int Bn = 8, Tn = 1024, Fn = 1024, Hn = 16, DKn = 64;
static constexpr int Mtot = Bn * Tn;  // 8192

DEVI u16 f2bf(float x) {
  unsigned u = __builtin_bit_cast(unsigned, x);
  u += 0x7fffu + ((u >> 16) & 1u);
  return (u16)(u >> 16);
}

DEVI u32 cvt_pk_bf16(float lo, float hi) {
  u32 r;
  asm("v_cvt_pk_bf16_f32 %0, %1, %2" : "=v"(r) : "v"(lo), "v"(hi));
  return r;
}

DEVI f32x4 mfma16(bf16x8 a, bf16x8 b, f32x4 c) {
  return __builtin_amdgcn_mfma_f32_16x16x32_bf16(a, b, c, 0, 0, 0);
}

typedef const __attribute__((address_space(1))) void GAS;
typedef __attribute__((address_space(3))) void LAS;
#define GLL16(gp, lp) __builtin_amdgcn_global_load_lds((GAS*)(gp), (LAS*)(lp), 16, 0, 0)

// ---------------- fp32 -> bf16 conversion (merged launches) ----------------
DEVI void cvt_chunk(const float* __restrict__ in, u16* __restrict__ out, int i) {
  const float4* p = reinterpret_cast<const float4*>(in + i);
  float4 a = p[0], b = p[1];
  float v[8] = {a.x, a.y, a.z, a.w, b.x, b.y, b.z, b.w};
  u16x8 r;
#pragma unroll
  for (int j = 0; j < 8; j++) r[j] = f2bf(v[j]);
  *reinterpret_cast<u16x8*>(out + i) = r;
}

__global__ __launch_bounds__(256) void cvt3(const float* __restrict__ a, const float* __restrict__ b,
                                            const float* __restrict__ c, u16* __restrict__ oa,
                                            u16* __restrict__ ob, u16* __restrict__ oc) {
  const int id = blockIdx.x * 256 + threadIdx.x;
  const int seg = id >> 20;                 // 8M elems / 8 per chunk = 2^20 chunks each
  const int off = (id & 1048575) * 8;
  const float* s = seg == 0 ? a : (seg == 1 ? b : c);
  u16* d = seg == 0 ? oa : (seg == 1 ? ob : oc);
  cvt_chunk(s, d, off);
}

__global__ __launch_bounds__(256) void cvt4(const float* __restrict__ a, const float* __restrict__ b,
                                            const float* __restrict__ c, const float* __restrict__ e,
                                            u16* __restrict__ oa, u16* __restrict__ ob,
                                            u16* __restrict__ oc, u16* __restrict__ oe) {
  const int id = blockIdx.x * 256 + threadIdx.x;
  const int seg = id >> 17;                 // 1M elems / 8 = 2^17 chunks each
  const int off = (id & 131071) * 8;
  const float* s = seg == 0 ? a : (seg == 1 ? b : (seg == 2 ? c : e));
  u16* d = seg == 0 ? oa : (seg == 1 ? ob : (seg == 2 ? oc : oe));
  cvt_chunk(s, d, off);
}

// ---------------- GEMM  C[M,N] = (A[M,K] * W[N,K]^T + bias) * oscale ----------------
// MODE 0: write bf16 (B,H,T,DK)  (Q/K proj; Q uses oscale = 1/sqrt(dk)*log2e)
//         SWAPPED mfma: acc[ni][mi], D rows=n via (g,j) -> u16x4 stores (4 consec dk)
// MODE 1: write bf16 (B,H,DK,T)  (V proj, transposed; unswapped, j=t contiguous)
// MODE 2: write fp32 (M,N) = (acc+bias)*mask[m]  (out proj; swapped -> float4 stores)
template <int MODE>
__global__ __launch_bounds__(256) void gemm_bt(const u16* __restrict__ A,
                                               const u16* __restrict__ Bw,
                                               const float* __restrict__ bias,
                                               const float* __restrict__ mask,
                                               u16* __restrict__ Obf,
                                               float* __restrict__ Of,
                                               float oscale) {
  constexpr int Kd = 1024;
  __shared__ u16 sA[2][128 * 32];
  __shared__ u16 sB[2][128 * 32];
  const int tid = threadIdx.x;
  const int l = tid & 63, w = tid >> 6;
  const int m0 = blockIdx.x * 128;  // 64 tiles
  const int n0 = blockIdx.y * 128;  // 8 tiles
  const int srow = l >> 2, sslot = l & 3;
  const int wr = w >> 1, wc = w & 1;
  const int lr = l & 15, g = l >> 4;

  f32x4 acc[4][4];
#pragma unroll
  for (int i = 0; i < 4; i++)
#pragma unroll
    for (int j = 0; j < 4; j++) acc[i][j] = f32x4{0.f, 0.f, 0.f, 0.f};

  auto stage = [&](int bf, int kt) {
    const u16* Ab = A + (size_t)m0 * Kd + kt * 32;
    const u16* Bb = Bw + (size_t)n0 * Kd + kt * 32;
#pragma unroll
    for (int i = 0; i < 2; i++) {
      int row = i * 64 + w * 16 + srow;
      GLL16(Ab + (size_t)row * Kd + sslot * 8, &sA[bf][i * 2048 + w * 512]);
      GLL16(Bb + (size_t)row * Kd + sslot * 8, &sB[bf][i * 2048 + w * 512]);
    }
  };

  stage(0, 0);
  __syncthreads();
  int cur = 0;
  for (int kt = 0; kt < 32; ++kt) {
    if (kt + 1 < 32) stage(cur ^ 1, kt + 1);
    bf16x8 af[4], bfr[4];
#pragma unroll
    for (int mi = 0; mi < 4; mi++)
      af[mi] = *reinterpret_cast<const bf16x8*>(&sA[cur][(wr * 64 + mi * 16 + lr) * 32 + g * 8]);
#pragma unroll
    for (int ni = 0; ni < 4; ni++)
      bfr[ni] = *reinterpret_cast<const bf16x8*>(&sB[cur][(wc * 64 + ni * 16 + lr) * 32 + g * 8]);
#pragma unroll
    for (int mi = 0; mi < 4; mi++)
#pragma unroll
      for (int ni = 0; ni < 4; ni++) {
        if constexpr (MODE == 1)
          acc[mi][ni] = mfma16(af[mi], bfr[ni], acc[mi][ni]);
        else
          acc[ni][mi] = mfma16(bfr[ni], af[mi], acc[ni][mi]);
      }
    __syncthreads();
    cur ^= 1;
  }

  if constexpr (MODE == 1) {
    // unswapped: rows=m via (g,j), cols=n via lr; j = t contiguous in V^T output
#pragma unroll
    for (int ni = 0; ni < 4; ni++) {
      const int n = n0 + wc * 64 + ni * 16 + lr;
      const float bv = bias[n];
      const int h = n >> 6, dk = n & 63;
#pragma unroll
      for (int mi = 0; mi < 4; mi++) {
        const int mb = m0 + wr * 64 + mi * 16 + g * 4;
        u16x4 pk;
#pragma unroll
        for (int j = 0; j < 4; j++) pk[j] = f2bf(acc[mi][ni][j] + bv);
        const int b = mb >> 10, t = mb & 1023;
        size_t idx = (((size_t)b * 16 + h) * 64 + dk) * 1024 + t;
        *reinterpret_cast<u16x4*>(Obf + idx) = pk;
      }
    }
  } else {
    // swapped: rows=n via (g,j) -> 4 consecutive n per lane
#pragma unroll
    for (int ni = 0; ni < 4; ni++) {
      const int nb = n0 + wc * 64 + ni * 16 + g * 4;
      const float4 b4 = *reinterpret_cast<const float4*>(&bias[nb]);
#pragma unroll
      for (int mi = 0; mi < 4; mi++) {
        const int m = m0 + wr * 64 + mi * 16 + lr;
        const f32x4 a = acc[ni][mi];
        if constexpr (MODE == 0) {
          const int b = m >> 10, t = m & 1023;
          const int h = nb >> 6, dk0 = nb & 63;
          u16x4 pk;
          pk[0] = f2bf((a[0] + b4.x) * oscale);
          pk[1] = f2bf((a[1] + b4.y) * oscale);
          pk[2] = f2bf((a[2] + b4.z) * oscale);
          pk[3] = f2bf((a[3] + b4.w) * oscale);
          *reinterpret_cast<u16x4*>(&Obf[((((size_t)b * 16 + h) * 1024 + t) * 64) + dk0]) = pk;
        } else {
          const float mk = mask[m];
          float4 o;
          o.x = (a[0] + b4.x) * mk;
          o.y = (a[1] + b4.y) * mk;
          o.z = (a[2] + b4.z) * mk;
          o.w = (a[3] + b4.w) * mk;
          *reinterpret_cast<float4*>(&Of[(size_t)m * 1024 + nb]) = o;
        }
      }
    }
  }
}

// ---------------- flash attention ----------------
// grid 1024 (XCD-swizzled: each head's 8 q-blocks on one XCD). Block = 4 waves x
// 32 q-rows. K double-buffered LDS, V single-buffered (staged after B2, latency
// hidden under next QK+softmax), P per-wave LDS. 32 KB LDS -> 4+ blocks/CU.
// Swapped-operand softmax with defer-max (T13, THR=8 log2-domain).
__global__ __launch_bounds__(256, 4) void flash_attn(const u16* __restrict__ Qb,
                                                     const u16* __restrict__ Kb,
                                                     const u16* __restrict__ Vt,
                                                     u16* __restrict__ ctx) {
  __shared__ u16 sK[2][64 * 64];
  __shared__ u16 sV[64 * 64];
  __shared__ u16 pbuf[4][16 * 64];
  const int tid = threadIdx.x, l = tid & 63, w = tid >> 6;
  const int lr = l & 15, g = l >> 4;
  const int wg = ((blockIdx.x & 7) << 7) + (blockIdx.x >> 3);  // bijective XCD swizzle
  const int qt = wg & 7, bh = wg >> 3;
  const u16* Qh = Qb + (size_t)bh * (Tn * DKn);
  const u16* Kh = Kb + (size_t)bh * (Tn * DKn);
  const u16* Vh = Vt + (size_t)bh * (Tn * DKn);

  bf16x8 aq[2][2];
  int qrow[2];
#pragma unroll
  for (int qg = 0; qg < 2; qg++) {
    qrow[qg] = qt * 128 + w * 32 + qg * 16 + lr;
    aq[qg][0] = *reinterpret_cast<const bf16x8*>(Qh + (size_t)qrow[qg] * 64 + g * 8);
    aq[qg][1] = *reinterpret_cast<const bf16x8*>(Qh + (size_t)qrow[qg] * 64 + 32 + g * 8);
  }

  float mrow[2] = {-1e30f, -1e30f}, lsum[2] = {0.f, 0.f};
  f32x4 of[2][4];
#pragma unroll
  for (int qg = 0; qg < 2; qg++)
#pragma unroll
    for (int c = 0; c < 4; c++) of[qg][c] = f32x4{0.f, 0.f, 0.f, 0.f};

  char* pb = (char*)&pbuf[w][0];
  const int sw = (lr & 7) << 4;
  int wadr[4];
#pragma unroll
  for (int c = 0; c < 4; c++) wadr[c] = lr * 128 + (((c * 16 + g * 4) * 2) ^ sw);
  const int radr0 = lr * 128 + ((g * 16) ^ sw);
  const int radr1 = lr * 128 + ((64 + g * 16) ^ sw);

  // K/V tiles: linear LDS dest, source chunk pre-XOR'd by (row&7) so swizzled
  // ds_read_b128 lands on the right data.
  auto stageK = [&](int buf, int kv0) {
#pragma unroll
    for (int i = 0; i < 2; i++) {
      const int tt = i * 256 + tid;
      const int r = tt >> 3;
      const int c = (tt & 7) ^ (r & 7);
      GLL16((const char*)Kh + ((size_t)(kv0 + r) << 7) + (c << 4),
            (char*)&sK[buf][0] + i * 4096 + w * 1024);
    }
  };
  auto stageV = [&](int kv0) {
#pragma unroll
    for (int i = 0; i < 2; i++) {
      const int tt = i * 256 + tid;
      const int r = tt >> 3;
      const int c = (tt & 7) ^ (r & 7);
      GLL16((const char*)Vh + ((size_t)r << 11) + kv0 * 2 + (c << 4),
            (char*)&sV[0] + i * 4096 + w * 1024);
    }
  };

  stageK(0, 0);
  stageV(0);
  __syncthreads();
  int cur = 0;

  for (int t = 0; t < 16; t++) {
    if (t < 15) stageK(cur ^ 1, (t + 1) * 64);
    const char* kb = (const char*)&sK[cur][0];
    const char* vb = (const char*)&sV[0];

    // S^T = K . Q^T for both q-groups (Q pre-scaled by 1/sqrt(dk)*log2e)
    f32x4 sf[2][4];
    __builtin_amdgcn_s_setprio(1);
#pragma unroll
    for (int c = 0; c < 4; c++) {
      const char* kr = kb + (c * 16 + lr) * 128;
      bf16x8 k0 = *reinterpret_cast<const bf16x8*>(kr + ((g * 16) ^ sw));
      bf16x8 k1 = *reinterpret_cast<const bf16x8*>(kr + ((64 + g * 16) ^ sw));
      f32x4 z0 = mfma16(k0, aq[0][0], f32x4{0.f, 0.f, 0.f, 0.f});
      sf[0][c] = mfma16(k1, aq[0][1], z0);
      f32x4 z1 = mfma16(k0, aq[1][0], f32x4{0.f, 0.f, 0.f, 0.f});
      sf[1][c] = mfma16(k1, aq[1][1], z1);
    }
    __builtin_amdgcn_s_setprio(0);

    bf16x8 ap[2][2];
#pragma unroll
    for (int qg = 0; qg < 2; qg++) {
      // defer-max online softmax (per-lane partial max is enough for the gate)
      f32x4 mx4 = sf[qg][0];
#pragma unroll
      for (int c = 1; c < 4; c++)
#pragma unroll
        for (int j = 0; j < 4; j++) mx4[j] = fmaxf(mx4[j], sf[qg][c][j]);
      const float pmax = fmaxf(fmaxf(mx4[0], mx4[1]), fmaxf(mx4[2], mx4[3]));
      if (__any(pmax > mrow[qg] + 8.0f)) {
        float mx = pmax;
        mx = fmaxf(mx, __shfl_xor(mx, 16));
        mx = fmaxf(mx, __shfl_xor(mx, 32));
        const float mn = fmaxf(mrow[qg], mx);
        const float alpha = exp2f(mrow[qg] - mn);
        mrow[qg] = mn;
        lsum[qg] *= alpha;
#pragma unroll
        for (int c = 0; c < 4; c++)
#pragma unroll
          for (int j = 0; j < 4; j++) of[qg][c][j] *= alpha;
      }
      const float mn = mrow[qg];
      float rs = 0.f;
#pragma unroll
      for (int c = 0; c < 4; c++)
#pragma unroll
        for (int j = 0; j < 4; j++) {
          float p = exp2f(sf[qg][c][j] - mn);
          sf[qg][c][j] = p;
          rs += p;
        }
      lsum[qg] += rs;

      // P -> per-wave LDS rows [q=lr][kv] (b64, swizzled), re-read as B-frags
#pragma unroll
      for (int c = 0; c < 4; c++) {
        uint2 pk;
        pk.x = cvt_pk_bf16(sf[qg][c][0], sf[qg][c][1]);
        pk.y = cvt_pk_bf16(sf[qg][c][2], sf[qg][c][3]);
        *reinterpret_cast<uint2*>(pb + wadr[c]) = pk;
      }
      ap[qg][0] = *reinterpret_cast<const bf16x8*>(pb + radr0);
      ap[qg][1] = *reinterpret_cast<const bf16x8*>(pb + radr1);
    }

    __syncthreads();  // B1: sV(t) writes from all waves drained & visible

    // O^T += V^T . P^T
    __builtin_amdgcn_s_setprio(1);
#pragma unroll
    for (int d0 = 0; d0 < 4; d0++) {
      const char* vr = vb + (d0 * 16 + lr) * 128;
      bf16x8 v0 = *reinterpret_cast<const bf16x8*>(vr + ((g * 16) ^ sw));
      bf16x8 v1 = *reinterpret_cast<const bf16x8*>(vr + ((64 + g * 16) ^ sw));
#pragma unroll
      for (int qg = 0; qg < 2; qg++) {
        f32x4 z = mfma16(v0, ap[qg][0], of[qg][d0]);
        of[qg][d0] = mfma16(v1, ap[qg][1], z);
      }
    }
    __builtin_amdgcn_s_setprio(0);

    __syncthreads();  // B2: all waves done reading sV(t) / sK[cur]
    if (t < 15) stageV((t + 1) * 64);
    cur ^= 1;
  }

  // epilogue: lsum group-reduce, normalize, store ctx (B*T, F) bf16
  const int b = bh >> 4, h = bh & 15;
#pragma unroll
  for (int qg = 0; qg < 2; qg++) {
    float ls = lsum[qg];
    ls += __shfl_xor(ls, 16);
    ls += __shfl_xor(ls, 32);
    const float inv = 1.0f / ls;
    const size_t base = ((size_t)b * 1024 + qrow[qg]) * 1024 + h * 64;
#pragma unroll
    for (int d0 = 0; d0 < 4; d0++) {
      uint2 pk;
      pk.x = cvt_pk_bf16(of[qg][d0][0] * inv, of[qg][d0][1] * inv);
      pk.y = cvt_pk_bf16(of[qg][d0][2] * inv, of[qg][d0][3] * inv);
      *reinterpret_cast<uint2*>(ctx + base + d0 * 16 + g * 4) = pk;
    }
  }
}

// ---------------- launch ----------------
extern "C" void kernel_launch(void* const* d_in, const int* in_sizes, int n_in,
                              void* d_out, int out_size, void* d_ws, size_t ws_size,
                              hipStream_t stream) {
  const float* query = (const float*)d_in[0];
  const float* key = (const float*)d_in[1];
  const float* value = (const float*)d_in[2];
  const float* mask = (const float*)d_in[3];
  const float* Wq = (const float*)d_in[4];
  const float* bq = (const float*)d_in[5];
  const float* Wk = (const float*)d_in[6];
  const float* bk = (const float*)d_in[7];
  const float* Wv = (const float*)d_in[8];
  const float* bv = (const float*)d_in[9];
  const float* Wo = (const float*)d_in[10];
  const float* bo = (const float*)d_in[11];
  (void)in_sizes; (void)n_in; (void)out_size; (void)ws_size;

  u16* ws = (u16*)d_ws;
  const size_t MB8 = (size_t)8 << 20;  // 8M u16 = 16 MB
  u16* Xq = ws;                        // reused as ctx after Q-proj
  u16* Xk = ws + MB8;
  u16* Xv = ws + 2 * MB8;
  u16* Wqb = ws + 3 * MB8;
  u16* Wkb = Wqb + (1 << 20);
  u16* Wvb = Wkb + (1 << 20);
  u16* Wob = Wvb + (1 << 20);
  u16* Qb = Wob + (1 << 20);
  u16* Kb = Qb + MB8;
  u16* Vtb = Kb + MB8;
  u16* ctx = Xq;

  cvt3<<<12288, 256, 0, stream>>>(query, key, value, Xq, Xk, Xv);
  cvt4<<<2048, 256, 0, stream>>>(Wq, Wk, Wv, Wo, Wqb, Wkb, Wvb, Wob);

  const float SC = 0.125f * 1.44269504089f;  // 1/sqrt(DK) * log2(e)
  dim3 gg(Mtot / 128, Fn / 128);
  gemm_bt<0><<<gg, 256, 0, stream>>>(Xq, Wqb, bq, nullptr, Qb, nullptr, SC);
  gemm_bt<0><<<gg, 256, 0, stream>>>(Xk, Wkb, bk, nullptr, Kb, nullptr, 1.0f);
  gemm_bt<1><<<gg, 256, 0, stream>>>(Xv, Wvb, bv, nullptr, Vtb, nullptr, 1.0f);

  flash_attn<<<Bn * Hn * (Tn / 128), 256, 0, stream>>>(Qb, Kb, Vtb, ctx);

  gemm_bt<2><<<gg, 256, 0, stream>>>(ctx, Wob, bo, mask, nullptr, (float*)d_out, 1.0f);
}

// Round 5
// 198.086 us; speedup vs baseline: 1.9693x; 1.0878x over previous
//
#include <hip/hip_runtime.h>
#include <hip/hip_bf16.h>

typedef unsigned short u16;
typedef unsigned int u32;
typedef __attribute__((ext_vector_type(8))) short bf16x8;
typedef __attribute__((ext_vector_type(8))) unsigned short u16x8;
typedef __attribute__((ext_vector_type(4))) unsigned short u16x4;
typedef __attribute__((ext_vector_type(4))) float f32x4;

#define DEVI __device__ __forceinline__

static constexpr int Bn = 8, Tn = 1024, Fn = 1024, Hn = 16, DKn = 64;
static constexpr int Mtot = Bn * Tn;  // 8192

DEVI u16 f2bf(float x) {
  unsigned u = __builtin_bit_cast(unsigned, x);
  u += 0x7fffu + ((u >> 16) & 1u);
  return (u16)(u >> 16);
}

DEVI u32 cvt_pk_bf16(float lo, float hi) {
  u32 r;
  asm("v_cvt_pk_bf16_f32 %0, %1, %2" : "=v"(r) : "v"(lo), "v"(hi));
  return r;
}

DEVI f32x4 mfma16(bf16x8 a, bf16x8 b, f32x4 c) {
  return __builtin_amdgcn_mfma_f32_16x16x32_bf16(a, b, c, 0, 0, 0);
}

typedef const __attribute__((address_space(1))) void GAS;
typedef __attribute__((address_space(3))) void LAS;
#define GLL16(gp, lp) __builtin_amdgcn_global_load_lds((GAS*)(gp), (LAS*)(lp), 16, 0, 0)

// ---------------- fp32 -> bf16 conversion (merged launches) ----------------
DEVI void cvt_chunk(const float* __restrict__ in, u16* __restrict__ out, int i) {
  const float4* p = reinterpret_cast<const float4*>(in + i);
  float4 a = p[0], b = p[1];
  float v[8] = {a.x, a.y, a.z, a.w, b.x, b.y, b.z, b.w};
  u16x8 r;
#pragma unroll
  for (int j = 0; j < 8; j++) r[j] = f2bf(v[j]);
  *reinterpret_cast<u16x8*>(out + i) = r;
}

__global__ __launch_bounds__(256) void cvt3(const float* __restrict__ a, const float* __restrict__ b,
                                            const float* __restrict__ c, u16* __restrict__ oa,
                                            u16* __restrict__ ob, u16* __restrict__ oc) {
  const int id = blockIdx.x * 256 + threadIdx.x;
  const int seg = id >> 20;                 // 8M elems / 8 per chunk = 2^20 chunks each
  const int off = (id & 1048575) * 8;
  const float* s = seg == 0 ? a : (seg == 1 ? b : c);
  u16* d = seg == 0 ? oa : (seg == 1 ? ob : oc);
  cvt_chunk(s, d, off);
}

__global__ __launch_bounds__(256) void cvt4(const float* __restrict__ a, const float* __restrict__ b,
                                            const float* __restrict__ c, const float* __restrict__ e,
                                            u16* __restrict__ oa, u16* __restrict__ ob,
                                            u16* __restrict__ oc, u16* __restrict__ oe) {
  const int id = blockIdx.x * 256 + threadIdx.x;
  const int seg = id >> 17;                 // 1M elems / 8 = 2^17 chunks each
  const int off = (id & 131071) * 8;
  const float* s = seg == 0 ? a : (seg == 1 ? b : (seg == 2 ? c : e));
  u16* d = seg == 0 ? oa : (seg == 1 ? ob : (seg == 2 ? oc : oe));
  cvt_chunk(s, d, off);
}

// ---------------- GEMM  C[M,N] = (A[M,K] * W[N,K]^T + bias) * oscale ----------------
// Counted-vmcnt schedule (T3+T4): BM=256 BN=128 BK=64, 512 thr = 8 waves (4Mx2N,
// 64x64/wave), LDS 96KB dbuf. Per K-tile: issue next tile's 6 global_load_lds ->
// s_waitcnt vmcnt(6) (never drain to 0 in-loop) -> s_barrier -> 2 phases of
// {8 swizzled ds_read_b128 -> setprio(1) 16 MFMA setprio(0)} -> s_barrier.
// T2 XOR-swizzle: LDS slot (r, s) holds global chunk (r, s^(r&7)); read byte
// = row*128 + ((ks*64+g*16) ^ ((row&7)<<4))  => conflict-free b128.
// MODE 0: write bf16 (B,H,T,DK)  (Q/K proj; Q pre-scaled by 1/sqrt(dk)*log2e)
//         swapped mfma: acc[ni][mi], rows=n via (g,j) -> u16x4 stores
// MODE 1: write bf16 (B,H,DK,T)  (V proj, transposed; unswapped, j=t contiguous)
// MODE 2: write fp32 (M,N) = (acc+bias)*mask[m]  (swapped -> float4 stores)
template <int MODE>
__global__ __launch_bounds__(512, 1) void gemm8(const u16* __restrict__ A,
                                                const u16* __restrict__ Bw,
                                                const float* __restrict__ bias,
                                                const float* __restrict__ mask,
                                                u16* __restrict__ Obf,
                                                float* __restrict__ Of,
                                                float oscale) {
  constexpr int Kd = 1024;
  __shared__ u16 sA[2][256 * 64];
  __shared__ u16 sB[2][128 * 64];
  const int tid = threadIdx.x;
  const int l = tid & 63, w = tid >> 6;
  const int wm = w >> 1, wn = w & 1;
  const int lr = l & 15, g = l >> 4;
  // XCD swizzle: 256 blocks, 32/XCD share bm-group (A panel + full W = 4MB L2)
  const int bid = blockIdx.x;
  const int wg = (bid & 7) * 32 + (bid >> 3);
  const int m0 = (wg >> 3) * 256, n0 = (wg & 7) * 128;

  f32x4 acc[4][4];
#pragma unroll
  for (int i = 0; i < 4; i++)
#pragma unroll
    for (int j = 0; j < 4; j++) acc[i][j] = f32x4{0.f, 0.f, 0.f, 0.f};

  // per-thread staging source offsets (inverse-swizzled global chunks)
  int aoff[4], boff[2];
#pragma unroll
  for (int i = 0; i < 4; i++) {
    const int c = i * 512 + tid;
    const int r = c >> 3, cc = (c & 7) ^ (r & 7);
    aoff[i] = r * Kd + cc * 8;
  }
#pragma unroll
  for (int i = 0; i < 2; i++) {
    const int c = i * 512 + tid;
    const int r = c >> 3, cc = (c & 7) ^ (r & 7);
    boff[i] = r * Kd + cc * 8;
  }
  const u16* Abase = A + (size_t)m0 * Kd;
  const u16* Bbase = Bw + (size_t)n0 * Kd;

  auto stage = [&](int buf, int kt) {
#pragma unroll
    for (int i = 0; i < 4; i++)
      GLL16(Abase + kt * 64 + aoff[i], (char*)&sA[buf][0] + (i * 512 + w * 64) * 16);
#pragma unroll
    for (int i = 0; i < 2; i++)
      GLL16(Bbase + kt * 64 + boff[i], (char*)&sB[buf][0] + (i * 512 + w * 64) * 16);
  };

  stage(0, 0);
  for (int t = 0; t < 16; ++t) {
    const int cur = t & 1;
    if (t < 15) {
      stage(cur ^ 1, t + 1);
      asm volatile("s_waitcnt vmcnt(6)" ::: "memory");
    } else {
      asm volatile("s_waitcnt vmcnt(0)" ::: "memory");
    }
    asm volatile("s_barrier" ::: "memory");
#pragma unroll
    for (int ks = 0; ks < 2; ks++) {
      bf16x8 af[4], bfr[4];
#pragma unroll
      for (int mi = 0; mi < 4; mi++) {
        const int row = wm * 64 + mi * 16 + lr;
        af[mi] = *reinterpret_cast<const bf16x8*>(
            (const char*)&sA[cur][0] + row * 128 + ((ks * 64 + g * 16) ^ ((row & 7) << 4)));
      }
#pragma unroll
      for (int ni = 0; ni < 4; ni++) {
        const int row = wn * 64 + ni * 16 + lr;
        bfr[ni] = *reinterpret_cast<const bf16x8*>(
            (const char*)&sB[cur][0] + row * 128 + ((ks * 64 + g * 16) ^ ((row & 7) << 4)));
      }
      __builtin_amdgcn_s_setprio(1);
#pragma unroll
      for (int mi = 0; mi < 4; mi++)
#pragma unroll
        for (int ni = 0; ni < 4; ni++) {
          if constexpr (MODE == 1)
            acc[mi][ni] = mfma16(af[mi], bfr[ni], acc[mi][ni]);
          else
            acc[ni][mi] = mfma16(bfr[ni], af[mi], acc[ni][mi]);
        }
      __builtin_amdgcn_s_setprio(0);
    }
    asm volatile("s_barrier" ::: "memory");
  }

  if constexpr (MODE == 1) {
    // unswapped: rows=m via (g,j), cols=n via lr; j = t contiguous in V^T output
#pragma unroll
    for (int ni = 0; ni < 4; ni++) {
      const int n = n0 + wn * 64 + ni * 16 + lr;
      const float bv = bias[n];
      const int h = n >> 6, dk = n & 63;
#pragma unroll
      for (int mi = 0; mi < 4; mi++) {
        const int mb = m0 + wm * 64 + mi * 16 + g * 4;
        u16x4 pk;
#pragma unroll
        for (int j = 0; j < 4; j++) pk[j] = f2bf(acc[mi][ni][j] + bv);
        const int b = mb >> 10, tt = mb & 1023;
        size_t idx = (((size_t)b * 16 + h) * 64 + dk) * 1024 + tt;
        *reinterpret_cast<u16x4*>(Obf + idx) = pk;
      }
    }
  } else {
    // swapped: rows=n via (g,j) -> 4 consecutive n per lane
#pragma unroll
    for (int ni = 0; ni < 4; ni++) {
      const int nb = n0 + wn * 64 + ni * 16 + g * 4;
      const float4 b4 = *reinterpret_cast<const float4*>(&bias[nb]);
#pragma unroll
      for (int mi = 0; mi < 4; mi++) {
        const int m = m0 + wm * 64 + mi * 16 + lr;
        const f32x4 a = acc[ni][mi];
        if constexpr (MODE == 0) {
          const int b = m >> 10, tt = m & 1023;
          const int h = nb >> 6, dk0 = nb & 63;
          u16x4 pk;
          pk[0] = f2bf((a[0] + b4.x) * oscale);
          pk[1] = f2bf((a[1] + b4.y) * oscale);
          pk[2] = f2bf((a[2] + b4.z) * oscale);
          pk[3] = f2bf((a[3] + b4.w) * oscale);
          *reinterpret_cast<u16x4*>(&Obf[((((size_t)b * 16 + h) * 1024 + tt) * 64) + dk0]) = pk;
        } else {
          const float mk = mask[m];
          float4 o;
          o.x = (a[0] + b4.x) * mk;
          o.y = (a[1] + b4.y) * mk;
          o.z = (a[2] + b4.z) * mk;
          o.w = (a[3] + b4.w) * mk;
          *reinterpret_cast<float4*>(&Of[(size_t)m * 1024 + nb]) = o;
        }
      }
    }
  }
}

// ---------------- flash attention (unchanged from R4) ----------------
__global__ __launch_bounds__(256, 4) void flash_attn(const u16* __restrict__ Qb,
                                                     const u16* __restrict__ Kb,
                                                     const u16* __restrict__ Vt,
                                                     u16* __restrict__ ctx) {
  __shared__ u16 sK[2][64 * 64];
  __shared__ u16 sV[64 * 64];
  __shared__ u16 pbuf[4][16 * 64];
  const int tid = threadIdx.x, l = tid & 63, w = tid >> 6;
  const int lr = l & 15, g = l >> 4;
  const int wg = ((blockIdx.x & 7) << 7) + (blockIdx.x >> 3);  // bijective XCD swizzle
  const int qt = wg & 7, bh = wg >> 3;
  const u16* Qh = Qb + (size_t)bh * (Tn * DKn);
  const u16* Kh = Kb + (size_t)bh * (Tn * DKn);
  const u16* Vh = Vt + (size_t)bh * (Tn * DKn);

  bf16x8 aq[2][2];
  int qrow[2];
#pragma unroll
  for (int qg = 0; qg < 2; qg++) {
    qrow[qg] = qt * 128 + w * 32 + qg * 16 + lr;
    aq[qg][0] = *reinterpret_cast<const bf16x8*>(Qh + (size_t)qrow[qg] * 64 + g * 8);
    aq[qg][1] = *reinterpret_cast<const bf16x8*>(Qh + (size_t)qrow[qg] * 64 + 32 + g * 8);
  }

  float mrow[2] = {-1e30f, -1e30f}, lsum[2] = {0.f, 0.f};
  f32x4 of[2][4];
#pragma unroll
  for (int qg = 0; qg < 2; qg++)
#pragma unroll
    for (int c = 0; c < 4; c++) of[qg][c] = f32x4{0.f, 0.f, 0.f, 0.f};

  char* pb = (char*)&pbuf[w][0];
  const int sw = (lr & 7) << 4;
  int wadr[4];
#pragma unroll
  for (int c = 0; c < 4; c++) wadr[c] = lr * 128 + (((c * 16 + g * 4) * 2) ^ sw);
  const int radr0 = lr * 128 + ((g * 16) ^ sw);
  const int radr1 = lr * 128 + ((64 + g * 16) ^ sw);

  auto stageK = [&](int buf, int kv0) {
#pragma unroll
    for (int i = 0; i < 2; i++) {
      const int tt = i * 256 + tid;
      const int r = tt >> 3;
      const int c = (tt & 7) ^ (r & 7);
      GLL16((const char*)Kh + ((size_t)(kv0 + r) << 7) + (c << 4),
            (char*)&sK[buf][0] + i * 4096 + w * 1024);
    }
  };
  auto stageV = [&](int kv0) {
#pragma unroll
    for (int i = 0; i < 2; i++) {
      const int tt = i * 256 + tid;
      const int r = tt >> 3;
      const int c = (tt & 7) ^ (r & 7);
      GLL16((const char*)Vh + ((size_t)r << 11) + kv0 * 2 + (c << 4),
            (char*)&sV[0] + i * 4096 + w * 1024);
    }
  };

  stageK(0, 0);
  stageV(0);
  __syncthreads();
  int cur = 0;

  for (int t = 0; t < 16; t++) {
    if (t < 15) stageK(cur ^ 1, (t + 1) * 64);
    const char* kb = (const char*)&sK[cur][0];
    const char* vb = (const char*)&sV[0];

    // S^T = K . Q^T for both q-groups (Q pre-scaled by 1/sqrt(dk)*log2e)
    f32x4 sf[2][4];
    __builtin_amdgcn_s_setprio(1);
#pragma unroll
    for (int c = 0; c < 4; c++) {
      const char* kr = kb + (c * 16 + lr) * 128;
      bf16x8 k0 = *reinterpret_cast<const bf16x8*>(kr + ((g * 16) ^ sw));
      bf16x8 k1 = *reinterpret_cast<const bf16x8*>(kr + ((64 + g * 16) ^ sw));
      f32x4 z0 = mfma16(k0, aq[0][0], f32x4{0.f, 0.f, 0.f, 0.f});
      sf[0][c] = mfma16(k1, aq[0][1], z0);
      f32x4 z1 = mfma16(k0, aq[1][0], f32x4{0.f, 0.f, 0.f, 0.f});
      sf[1][c] = mfma16(k1, aq[1][1], z1);
    }
    __builtin_amdgcn_s_setprio(0);

    bf16x8 ap[2][2];
#pragma unroll
    for (int qg = 0; qg < 2; qg++) {
      f32x4 mx4 = sf[qg][0];
#pragma unroll
      for (int c = 1; c < 4; c++)
#pragma unroll
        for (int j = 0; j < 4; j++) mx4[j] = fmaxf(mx4[j], sf[qg][c][j]);
      const float pmax = fmaxf(fmaxf(mx4[0], mx4[1]), fmaxf(mx4[2], mx4[3]));
      if (__any(pmax > mrow[qg] + 8.0f)) {
        float mx = pmax;
        mx = fmaxf(mx, __shfl_xor(mx, 16));
        mx = fmaxf(mx, __shfl_xor(mx, 32));
        const float mn = fmaxf(mrow[qg], mx);
        const float alpha = exp2f(mrow[qg] - mn);
        mrow[qg] = mn;
        lsum[qg] *= alpha;
#pragma unroll
        for (int c = 0; c < 4; c++)
#pragma unroll
          for (int j = 0; j < 4; j++) of[qg][c][j] *= alpha;
      }
      const float mn = mrow[qg];
      float rs = 0.f;
#pragma unroll
      for (int c = 0; c < 4; c++)
#pragma unroll
        for (int j = 0; j < 4; j++) {
          float p = exp2f(sf[qg][c][j] - mn);
          sf[qg][c][j] = p;
          rs += p;
        }
      lsum[qg] += rs;

#pragma unroll
      for (int c = 0; c < 4; c++) {
        uint2 pk;
        pk.x = cvt_pk_bf16(sf[qg][c][0], sf[qg][c][1]);
        pk.y = cvt_pk_bf16(sf[qg][c][2], sf[qg][c][3]);
        *reinterpret_cast<uint2*>(pb + wadr[c]) = pk;
      }
      ap[qg][0] = *reinterpret_cast<const bf16x8*>(pb + radr0);
      ap[qg][1] = *reinterpret_cast<const bf16x8*>(pb + radr1);
    }

    __syncthreads();  // B1: sV(t) writes from all waves drained & visible

    __builtin_amdgcn_s_setprio(1);
#pragma unroll
    for (int d0 = 0; d0 < 4; d0++) {
      const char* vr = vb + (d0 * 16 + lr) * 128;
      bf16x8 v0 = *reinterpret_cast<const bf16x8*>(vr + ((g * 16) ^ sw));
      bf16x8 v1 = *reinterpret_cast<const bf16x8*>(vr + ((64 + g * 16) ^ sw));
#pragma unroll
      for (int qg = 0; qg < 2; qg++) {
        f32x4 z = mfma16(v0, ap[qg][0], of[qg][d0]);
        of[qg][d0] = mfma16(v1, ap[qg][1], z);
      }
    }
    __builtin_amdgcn_s_setprio(0);

    __syncthreads();  // B2: all waves done reading sV(t) / sK[cur]
    if (t < 15) stageV((t + 1) * 64);
    cur ^= 1;
  }

  const int b = bh >> 4, h = bh & 15;
#pragma unroll
  for (int qg = 0; qg < 2; qg++) {
    float ls = lsum[qg];
    ls += __shfl_xor(ls, 16);
    ls += __shfl_xor(ls, 32);
    const float inv = 1.0f / ls;
    const size_t base = ((size_t)b * 1024 + qrow[qg]) * 1024 + h * 64;
#pragma unroll
    for (int d0 = 0; d0 < 4; d0++) {
      uint2 pk;
      pk.x = cvt_pk_bf16(of[qg][d0][0] * inv, of[qg][d0][1] * inv);
      pk.y = cvt_pk_bf16(of[qg][d0][2] * inv, of[qg][d0][3] * inv);
      *reinterpret_cast<uint2*>(ctx + base + d0 * 16 + g * 4) = pk;
    }
  }
}

// ---------------- launch ----------------
extern "C" void kernel_launch(void* const* d_in, const int* in_sizes, int n_in,
                              void* d_out, int out_size, void* d_ws, size_t ws_size,
                              hipStream_t stream) {
  const float* query = (const float*)d_in[0];
  const float* key = (const float*)d_in[1];
  const float* value = (const float*)d_in[2];
  const float* mask = (const float*)d_in[3];
  const float* Wq = (const float*)d_in[4];
  const float* bq = (const float*)d_in[5];
  const float* Wk = (const float*)d_in[6];
  const float* bk = (const float*)d_in[7];
  const float* Wv = (const float*)d_in[8];
  const float* bv = (const float*)d_in[9];
  const float* Wo = (const float*)d_in[10];
  const float* bo = (const float*)d_in[11];
  (void)in_sizes; (void)n_in; (void)out_size; (void)ws_size;

  u16* ws = (u16*)d_ws;
  const size_t MB8 = (size_t)8 << 20;  // 8M u16 = 16 MB
  u16* Xq = ws;                        // reused as ctx after Q-proj
  u16* Xk = ws + MB8;
  u16* Xv = ws + 2 * MB8;
  u16* Wqb = ws + 3 * MB8;
  u16* Wkb = Wqb + (1 << 20);
  u16* Wvb = Wkb + (1 << 20);
  u16* Wob = Wvb + (1 << 20);
  u16* Qb = Wob + (1 << 20);
  u16* Kb = Qb + MB8;
  u16* Vtb = Kb + MB8;
  u16* ctx = Xq;

  cvt3<<<12288, 256, 0, stream>>>(query, key, value, Xq, Xk, Xv);
  cvt4<<<2048, 256, 0, stream>>>(Wq, Wk, Wv, Wo, Wqb, Wkb, Wvb, Wob);

  const float SC = 0.125f * 1.44269504089f;  // 1/sqrt(DK) * log2(e)
  const int ng = (Mtot / 256) * (Fn / 128);  // 256 blocks
  gemm8<0><<<ng, 512, 0, stream>>>(Xq, Wqb, bq, nullptr, Qb, nullptr, SC);
  gemm8<0><<<ng, 512, 0, stream>>>(Xk, Wkb, bk, nullptr, Kb, nullptr, 1.0f);
  gemm8<1><<<ng, 512, 0, stream>>>(Xv, Wvb, bv, nullptr, Vtb, nullptr, 1.0f);

  flash_attn<<<Bn * Hn * (Tn / 128), 256, 0, stream>>>(Qb, Kb, Vtb, ctx);

  gemm8<2><<<ng, 512, 0, stream>>>(ctx, Wob, bo, mask, nullptr, (float*)d_out, 1.0f);
}